// Round 2
// baseline (215.470 us; speedup 1.0000x reference)
//
#include <hip/hip_runtime.h>
#include <cstdint>

// Fused single-head attention, B=4 S=2048 D=1024, fp32 in/out, bf16 MFMA compute.
// Pipeline: cast/pack -> QKV GEMM (v transposed) -> scores GEMM -> softmax -> PV GEMM.
// GEMM engine: 256-row tile, 512 thr (8 waves, 2M x 4N), BK=32, 4-deep LDS ring,
// counted vmcnt (never drains to 0 in steady state), raw s_barrier, setprio on MFMA.

typedef unsigned short u16;
typedef __attribute__((ext_vector_type(4))) float f32x4;
typedef __attribute__((ext_vector_type(8))) __bf16 bf16x8;

#define AS1(p) ((const __attribute__((address_space(1))) void*)(p))
#define AS3(p) ((__attribute__((address_space(3))) void*)(p))

#define SEQ 2048
#define DM 1024

// ---------- bf16 bit helpers ----------
__device__ __forceinline__ u16 f2b(float f) {
  uint32_t u = __builtin_bit_cast(uint32_t, f);
  u += 0x7FFFu + ((u >> 16) & 1u);   // RNE
  return (u16)(u >> 16);
}
__device__ __forceinline__ float b2f(uint32_t bits16) {
  return __builtin_bit_cast(float, bits16 << 16);
}

// ---------- converts ----------
__global__ __launch_bounds__(256) void cvt_x_kernel(const float* __restrict__ x,
                                                    u16* __restrict__ xb) {
  int i = (blockIdx.x * 256 + threadIdx.x) * 4;
  float4 v = *(const float4*)(x + i);
  ushort4 o;
  o.x = f2b(v.x); o.y = f2b(v.y); o.z = f2b(v.z); o.w = f2b(v.w);
  *(ushort4*)(xb + i) = o;
}

__global__ __launch_bounds__(256) void pack_w_kernel(const float* __restrict__ Wq,
                                                     const float* __restrict__ Wk,
                                                     const float* __restrict__ Wv,
                                                     u16* __restrict__ wcat) {
  int i = (blockIdx.x * 256 + threadIdx.x) * 4;   // over 3*2^20 elems
  const float* src;
  int j;
  if (i < (1 << 20))      { src = Wq; j = i; }
  else if (i < (2 << 20)) { src = Wk; j = i - (1 << 20); }
  else                    { src = Wv; j = i - (2 << 20); }
  float4 v = *(const float4*)(src + j);
  ushort4 o;
  o.x = f2b(v.x); o.y = f2b(v.y); o.z = f2b(v.z); o.w = f2b(v.w);
  *(ushort4*)(wcat + i) = o;
}

// ---------- pipelined GEMM engine ----------
// C-tile = 256 x (NF*64).  A: [256][K] row-major (lda), Bt: [NF*64][K] row-major (ldb).
// Per wave: 128 rows x NF*16 cols -> acc[8][NF] of 16x16 frags.
// K-tile = 32.  LDS: 4-slot ring per operand; A slot 16 KB, B slot NF*4 KB.
// Rows in LDS are 64 B -> lanes spread evenly over bank slots (no conflicts).
// Pipeline: prefetch 3 K-tiles ahead; vmcnt leaves exactly the 2 newest tiles
// in flight at each phase's barrier, guaranteeing tile t+1 for the next phase.

#define PHASE(t, DO_STAGE, W)                                                   \
  {                                                                             \
    if (DO_STAGE) stage((t) + 3);                                               \
    const char* la = ldsA + ((t) & 3) * 16384 + wm * 8192;                      \
    const char* lb = ldsB + ((t) & 3) * (NF * 4096) + wn * (NF * 1024);         \
    bf16x8 af[8], bfr[NF];                                                      \
    _Pragma("unroll") for (int m = 0; m < 8; ++m)                               \
      af[m] = *(const bf16x8*)(la + (m * 16 + fr) * 64 + ch * 16);              \
    _Pragma("unroll") for (int n = 0; n < NF; ++n)                              \
      bfr[n] = *(const bf16x8*)(lb + (n * 16 + fr) * 64 + ch * 16);             \
    asm volatile("s_waitcnt vmcnt(%0)" :: "i"(W) : "memory");                   \
    __builtin_amdgcn_s_barrier();                                               \
    asm volatile("s_waitcnt lgkmcnt(0)" ::: "memory");                          \
    __builtin_amdgcn_sched_barrier(0);                                          \
    __builtin_amdgcn_s_setprio(1);                                              \
    _Pragma("unroll") for (int m = 0; m < 8; ++m)                               \
      _Pragma("unroll") for (int n = 0; n < NF; ++n)                            \
        acc[m][n] = __builtin_amdgcn_mfma_f32_16x16x32_bf16(af[m], bfr[n],      \
                                                            acc[m][n], 0, 0, 0);\
    __builtin_amdgcn_s_setprio(0);                                              \
    __builtin_amdgcn_s_barrier();                                               \
  }

template <int NF, int T>
__device__ __forceinline__ void gemm_engine(const u16* __restrict__ A,
                                            const u16* __restrict__ Bt,
                                            int lda, int ldb, char* lds,
                                            f32x4 (&acc)[8][NF], int tid) {
  constexpr int LPT = 2 + NF / 2;        // global_load_lds per thread per K-tile
  const int l = tid & 63;
  const int wm = (tid >> 6) >> 2, wn = (tid >> 6) & 3;
  const int fr = l & 15, ch = l >> 4;

  char* ldsA = lds;                       // 4 x 16384
  char* ldsB = lds + 65536;               // 4 x NF*4096

  // per-thread staging geometry: linear LDS byte o = tid*16 (+8192) maps to
  // source row o>>6, 16B-chunk (o>>4)&3 of the [rows][32] bf16 K-tile.
  const int oa0 = tid * 16, oa1 = tid * 16 + 8192;
  const u16* srcA0 = A + (oa0 >> 6) * lda + ((oa0 >> 4) & 3) * 8;
  const u16* srcA1 = A + (oa1 >> 6) * lda + ((oa1 >> 4) & 3) * 8;
  const u16* srcB0 = Bt + (oa0 >> 6) * ldb + ((oa0 >> 4) & 3) * 8;
  const u16* srcB1 = (NF == 4) ? (Bt + (oa1 >> 6) * ldb + ((oa1 >> 4) & 3) * 8)
                               : (const u16*)nullptr;
  const int wbase = (tid & ~63) * 16;     // wave-uniform LDS base (w*1024)

  auto stage = [&](int t) {
    const int b = t & 3;
    const int koff = t * 32;
    __builtin_amdgcn_global_load_lds(AS1(srcA0 + koff),
                                     AS3(ldsA + b * 16384 + wbase), 16, 0, 0);
    __builtin_amdgcn_global_load_lds(AS1(srcA1 + koff),
                                     AS3(ldsA + b * 16384 + 8192 + wbase), 16, 0, 0);
    __builtin_amdgcn_global_load_lds(AS1(srcB0 + koff),
                                     AS3(ldsB + b * (NF * 4096) + wbase), 16, 0, 0);
    if constexpr (NF == 4)
      __builtin_amdgcn_global_load_lds(AS1(srcB1 + koff),
                                       AS3(ldsB + b * (NF * 4096) + 8192 + wbase), 16, 0, 0);
  };

  stage(0); stage(1); stage(2);
#pragma unroll
  for (int m = 0; m < 8; ++m)
#pragma unroll
    for (int n = 0; n < NF; ++n)
#pragma unroll
      for (int j = 0; j < 4; ++j) acc[m][n][j] = 0.f;
  asm volatile("s_waitcnt vmcnt(%0)" :: "i"(2 * LPT) : "memory");
  __builtin_amdgcn_s_barrier();

  for (int t = 0; t < T - 3; ++t) PHASE(t, true, 2 * LPT)
  PHASE(T - 3, false, LPT)
  PHASE(T - 2, false, 0)
  PHASE(T - 1, false, 0)
}

// ---------- QKV GEMM: [8192 x 3072] = xb[8192x1024] * wcat[3072x1024]^T + bias ----------
__global__ __launch_bounds__(512, 2) void qkv_gemm(const u16* __restrict__ xb,
                                                   const u16* __restrict__ wcat,
                                                   const float* __restrict__ bq,
                                                   const float* __restrict__ bk,
                                                   const float* __restrict__ bv,
                                                   u16* __restrict__ qb,
                                                   u16* __restrict__ kb,
                                                   u16* __restrict__ vtb) {
  __shared__ __align__(16) char lds[131072];
  const int tid = threadIdx.x;
  const int bm = blockIdx.y * 256, bn = blockIdx.x * 256;
  f32x4 acc[8][4];
  gemm_engine<4, 32>(xb + bm * 1024, wcat + bn * 1024, 1024, 1024, lds, acc, tid);
  const int l = tid & 63;
  const int wm = (tid >> 6) >> 2, wn = (tid >> 6) & 3;
  const int which = bn >> 10;  // uniform per block
  const float* bias = (which == 0) ? bq : (which == 1) ? bk : bv;
#pragma unroll
  for (int m = 0; m < 8; ++m)
#pragma unroll
    for (int n = 0; n < 4; ++n) {
      int col = bn + wn * 64 + n * 16 + (l & 15);
      int e = col & 1023;
      float bval = bias[e];
#pragma unroll
      for (int j = 0; j < 4; ++j) {
        int row = bm + wm * 128 + m * 16 + (l >> 4) * 4 + j;
        u16 hb = f2b(acc[m][n][j] + bval);
        if (which == 0)      qb[row * 1024 + e] = hb;
        else if (which == 1) kb[row * 1024 + e] = hb;
        else { int b = row >> 11, s = row & 2047; vtb[(b << 21) + e * 2048 + s] = hb; }
      }
    }
}

// ---------- scores GEMM per batch: sb = (q * k^T) / 32, bf16 ----------
__global__ __launch_bounds__(512, 2) void scores_gemm(const u16* __restrict__ qb,
                                                      const u16* __restrict__ kb,
                                                      u16* __restrict__ sb) {
  __shared__ __align__(16) char lds[131072];
  const int tid = threadIdx.x;
  const int b = blockIdx.z;
  const int bm = blockIdx.y * 256, bn = blockIdx.x * 256;
  f32x4 acc[8][4];
  gemm_engine<4, 32>(qb + b * (SEQ * DM) + bm * 1024,
                     kb + b * (SEQ * DM) + bn * 1024, 1024, 1024, lds, acc, tid);
  u16* out = sb + (size_t)b * SEQ * SEQ;
  const int l = tid & 63;
  const int wm = (tid >> 6) >> 2, wn = (tid >> 6) & 3;
#pragma unroll
  for (int m = 0; m < 8; ++m)
#pragma unroll
    for (int n = 0; n < 4; ++n) {
      int col = bn + wn * 64 + n * 16 + (l & 15);
#pragma unroll
      for (int j = 0; j < 4; ++j) {
        int row = bm + wm * 128 + m * 16 + (l >> 4) * 4 + j;
        out[row * 2048 + col] = f2b(acc[m][n][j] * 0.03125f);
      }
    }
}

// ---------- row softmax: 2048-wide rows, bf16 in, bf16 out ----------
__global__ __launch_bounds__(256) void softmax_k(const u16* __restrict__ sb,
                                                 u16* __restrict__ pb) {
  __shared__ float red[8];
  int row = blockIdx.x;
  const u16* src = sb + (size_t)row * 2048;
  u16* dst = pb + (size_t)row * 2048;
  int t = threadIdx.x;
  uint4 raw = *(const uint4*)(src + t * 8);
  uint32_t rw[4] = {raw.x, raw.y, raw.z, raw.w};
  float v[8];
#pragma unroll
  for (int q = 0; q < 4; ++q) {
    v[2 * q]     = b2f(rw[q] & 0xFFFFu);
    v[2 * q + 1] = __builtin_bit_cast(float, rw[q] & 0xFFFF0000u);
  }
  float m = v[0];
#pragma unroll
  for (int j = 1; j < 8; ++j) m = fmaxf(m, v[j]);
  for (int off = 32; off; off >>= 1) m = fmaxf(m, __shfl_xor(m, off));
  int w = t >> 6, l = t & 63;
  if (l == 0) red[w] = m;
  __syncthreads();
  m = fmaxf(fmaxf(red[0], red[1]), fmaxf(red[2], red[3]));
  float e[8], s = 0.f;
#pragma unroll
  for (int j = 0; j < 8; ++j) { e[j] = __expf(v[j] - m); s += e[j]; }
  for (int off = 32; off; off >>= 1) s += __shfl_xor(s, off);
  if (l == 0) red[4 + w] = s;
  __syncthreads();
  s = (red[4] + red[5]) + (red[6] + red[7]);
  float inv = 1.0f / s;
  uint32_t o[4];
#pragma unroll
  for (int q = 0; q < 4; ++q) {
    uint32_t lo = f2b(e[2 * q] * inv);
    uint32_t hi = f2b(e[2 * q + 1] * inv);
    o[q] = lo | (hi << 16);
  }
  *(uint4*)(dst + t * 8) = make_uint4(o[0], o[1], o[2], o[3]);
}

// ---------- PV GEMM per batch: out = pb[2048x2048] * v[2048x1024], fp32 out ----------
// NF=2 (BN=128) so the grid is 8x8x4 = 256 blocks (full machine).
__global__ __launch_bounds__(512, 2) void pv_gemm(const u16* __restrict__ pb,
                                                  const u16* __restrict__ vtb,
                                                  float* __restrict__ out) {
  __shared__ __align__(16) char lds[98304];   // 64 KB A ring + 32 KB B ring
  const int tid = threadIdx.x;
  const int b = blockIdx.z;
  const int bm = blockIdx.y * 256, bn = blockIdx.x * 128;
  f32x4 acc[8][2];
  gemm_engine<2, 64>(pb + (size_t)b * SEQ * SEQ + bm * 2048,
                     vtb + (size_t)b * DM * SEQ + bn * 2048, 2048, 2048, lds, acc, tid);
  float* o = out + (size_t)b * SEQ * DM;
  const int l = tid & 63;
  const int wm = (tid >> 6) >> 2, wn = (tid >> 6) & 3;
#pragma unroll
  for (int m = 0; m < 8; ++m)
#pragma unroll
    for (int n = 0; n < 2; ++n) {
      int col = bn + wn * 32 + n * 16 + (l & 15);
#pragma unroll
      for (int j = 0; j < 4; ++j) {
        int row = bm + wm * 128 + m * 16 + (l >> 4) * 4 + j;
        o[row * 1024 + col] = acc[m][n][j];
      }
    }
}

// ---------- launch ----------
extern "C" void kernel_launch(void* const* d_in, const int* in_sizes, int n_in,
                              void* d_out, int out_size, void* d_ws, size_t ws_size,
                              hipStream_t stream) {
  const float* x  = (const float*)d_in[0];
  const float* Wq = (const float*)d_in[1];
  const float* bq = (const float*)d_in[2];
  const float* Wk = (const float*)d_in[3];
  const float* bk = (const float*)d_in[4];
  const float* Wv = (const float*)d_in[5];
  const float* bv = (const float*)d_in[6];
  float* out = (float*)d_out;

  char* ws = (char*)d_ws;
  u16* xb   = (u16*)(ws);                 // 16 MB  bf16 x            [8192][1024]
  u16* wcat = (u16*)(ws + 16777216);      //  6 MB  bf16 Wq|Wk|Wv     [3072][1024]
  u16* qb   = (u16*)(ws + 23068672);      // 16 MB  bf16 q            [4][2048][1024]
  u16* kb   = (u16*)(ws + 39845888);      // 16 MB  bf16 k            [4][2048][1024]
  u16* vtb  = (u16*)(ws + 56623104);      // 16 MB  bf16 v^T          [4][1024][2048]
  u16* sb   = (u16*)(ws + 73400320);      // 32 MB  bf16 scores       [4][2048][2048]
  u16* pb   = (u16*)(ws + 106954752);     // 32 MB  bf16 probs        [4][2048][2048]

  cvt_x_kernel<<<8192, 256, 0, stream>>>(x, xb);
  pack_w_kernel<<<3072, 256, 0, stream>>>(Wq, Wk, Wv, wcat);
  qkv_gemm<<<dim3(12, 32), 512, 0, stream>>>(xb, wcat, bq, bk, bv, qb, kb, vtb);
  scores_gemm<<<dim3(8, 8, 4), 512, 0, stream>>>(qb, kb, sb);
  softmax_k<<<8192, 256, 0, stream>>>(sb, pb);
  pv_gemm<<<dim3(8, 8, 4), 512, 0, stream>>>(pb, vtb, out);
}

// Round 3
// 197.246 us; speedup vs baseline: 1.0924x; 1.0924x over previous
//
#include <hip/hip_runtime.h>
#include <cstdint>

// Fused single-head attention, B=4 S=2048 D=1024, fp32 in/out, bf16 MFMA compute.
// Pipeline: cast/pack -> QKV GEMM (v transposed) -> scores GEMM -> softmax -> PV GEMM.
// GEMM engine: 256-row tiles, 512 thr (8 waves), BK=64 split into two 32-col
// half-phases; 2x2 half-region LDS ring with paired-row XOR swizzle
// (conflict-free ds_read_b128, verified by lane enumeration); counted vmcnt
// (never 0 in steady state); one raw s_barrier per phase; setprio around MFMA.

typedef unsigned short u16;
typedef __attribute__((ext_vector_type(4))) float f32x4;
typedef __attribute__((ext_vector_type(8))) __bf16 bf16x8;

#define AS1(p) ((const __attribute__((address_space(1))) void*)(p))
#define AS3(p) ((__attribute__((address_space(3))) void*)(p))

#define SEQ 2048
#define DM 1024

// ---------- bf16 bit helpers ----------
__device__ __forceinline__ u16 f2b(float f) {
  uint32_t u = __builtin_bit_cast(uint32_t, f);
  u += 0x7FFFu + ((u >> 16) & 1u);   // RNE
  return (u16)(u >> 16);
}
__device__ __forceinline__ float b2f(uint32_t bits16) {
  return __builtin_bit_cast(float, bits16 << 16);
}

// ---------- converts ----------
__global__ __launch_bounds__(256) void cvt_x_kernel(const float* __restrict__ x,
                                                    u16* __restrict__ xb) {
  int i = (blockIdx.x * 256 + threadIdx.x) * 4;
  float4 v = *(const float4*)(x + i);
  ushort4 o;
  o.x = f2b(v.x); o.y = f2b(v.y); o.z = f2b(v.z); o.w = f2b(v.w);
  *(ushort4*)(xb + i) = o;
}

__global__ __launch_bounds__(256) void pack_w_kernel(const float* __restrict__ Wq,
                                                     const float* __restrict__ Wk,
                                                     const float* __restrict__ Wv,
                                                     u16* __restrict__ wcat) {
  int i = (blockIdx.x * 256 + threadIdx.x) * 4;   // over 3*2^20 elems
  const float* src;
  int j;
  if (i < (1 << 20))      { src = Wq; j = i; }
  else if (i < (2 << 20)) { src = Wk; j = i - (1 << 20); }
  else                    { src = Wv; j = i - (2 << 20); }
  float4 v = *(const float4*)(src + j);
  ushort4 o;
  o.x = f2b(v.x); o.y = f2b(v.y); o.z = f2b(v.z); o.w = f2b(v.w);
  *(ushort4*)(wcat + i) = o;
}

// ---------- pipelined GEMM engine ----------
// Tile: BM = WGM*FM*16 rows x BN = WGN*FN*16 cols, 8 waves (WGM x WGN).
// K-tile = 64, processed as 2 half-phases of 32 k-cols.
// LDS per op: 4 half-regions (2 buf x 2 half), region = R rows x 32 cols bf16
//   = R*64 bytes, paired-row swizzled:
//   off(row, ch) = (row>>1)*128 + (((row&1)*4 + ch) ^ ((row>>1)&7))*16
// Phase i (t=i>>1, h=i&1, buf=t&1):
//   stage half(i+2) -> region(buf^1, h)   [LPH global_load_lds]
//   ds_read own frags of half i           [FM+FN x ds_read_b128, conflict-free]
//   vmcnt(LPH)  -> guarantees half(i+1); half(i+2) stays in flight
//   s_barrier; lgkmcnt(0); sched_barrier; setprio(1); FM*FN MFMA; setprio(0)

#define PH(T_, H_, BUF_, STG_, W_)                                              \
  {                                                                             \
    if (STG_) stage((T_) + 1, H_, (BUF_) ^ 1);                                  \
    const char* la = ldsA + ((BUF_) * 2 + (H_)) * SZA + wm * (FM * 1024) + tb;  \
    const char* lb = ldsB + ((BUF_) * 2 + (H_)) * SZB + wn * (FN * 1024) + tb;  \
    bf16x8 af[FM], bfr[FN];                                                     \
    _Pragma("unroll") for (int m = 0; m < FM; ++m)                              \
      af[m] = *(const bf16x8*)(la + m * 1024);                                  \
    _Pragma("unroll") for (int n = 0; n < FN; ++n)                              \
      bfr[n] = *(const bf16x8*)(lb + n * 1024);                                 \
    asm volatile("s_waitcnt vmcnt(%0)" :: "i"(W_) : "memory");                  \
    __builtin_amdgcn_s_barrier();                                               \
    asm volatile("s_waitcnt lgkmcnt(0)" ::: "memory");                          \
    __builtin_amdgcn_sched_barrier(0);                                          \
    __builtin_amdgcn_s_setprio(1);                                              \
    _Pragma("unroll") for (int m = 0; m < FM; ++m)                              \
      _Pragma("unroll") for (int n = 0; n < FN; ++n)                            \
        acc[m][n] = __builtin_amdgcn_mfma_f32_16x16x32_bf16(af[m], bfr[n],      \
                                                            acc[m][n], 0, 0, 0);\
    __builtin_amdgcn_s_setprio(0);                                              \
  }

template <int FM, int FN, int WGM, int WGN, int T>
__device__ __forceinline__ void gemm_engine(const u16* __restrict__ A,
                                            const u16* __restrict__ Bt,
                                            int lda, int ldb, char* lds,
                                            f32x4 (&acc)[FM][FN], int tid) {
  static_assert((T & 1) == 0, "T must be even");
  constexpr int RA  = WGM * FM * 16;     // rows of A staged per K-tile
  constexpr int RB  = WGN * FN * 16;     // rows of Bt staged per K-tile
  constexpr int SZA = RA * 64;           // bytes per A half-region
  constexpr int SZB = RB * 64;
  constexpr int JA  = RA / 128;          // global_load_lds per thread (A)
  constexpr int JB  = RB / 128;
  constexpr int LPH = JA + JB;

  char* ldsA = lds;
  char* ldsB = lds + 4 * SZA;

  const int l  = tid & 63;
  const int w  = tid >> 6;
  const int wm = w / WGN, wn = w % WGN;
  const int fr = l & 15, ch = l >> 4;
  // conflict-free frag-read base (per-thread constant)
  const int tb = ((fr >> 1) << 7) + (((((fr & 1) << 2) | ch) ^ (fr >> 1)) << 4);
  const int wbase = (tid & ~63) * 16;    // wave-uniform LDS base

  // staging: linear LDS offset o = j*8192 + tid*16 within a region; inverse
  // swizzle gives the global element to fetch so reads see swizzled layout.
  int aoff[JA], boff[JB];
#pragma unroll
  for (int j = 0; j < JA; ++j) {
    int o  = j * 8192 + tid * 16;
    int rp = o >> 7;
    int cl = ((o >> 4) & 7) ^ (rp & 7);
    aoff[j] = (rp * 2 + (cl >> 2)) * lda + (cl & 3) * 8;
  }
#pragma unroll
  for (int j = 0; j < JB; ++j) {
    int o  = j * 8192 + tid * 16;
    int rp = o >> 7;
    int cl = ((o >> 4) & 7) ^ (rp & 7);
    boff[j] = (rp * 2 + (cl >> 2)) * ldb + (cl & 3) * 8;
  }

  auto stage = [&](int t, int h, int buf) {
    const int ke = t * 64 + h * 32;      // element offset along K
#pragma unroll
    for (int j = 0; j < JA; ++j)
      __builtin_amdgcn_global_load_lds(AS1(A + aoff[j] + ke),
          AS3(ldsA + (buf * 2 + h) * SZA + j * 8192 + wbase), 16, 0, 0);
#pragma unroll
    for (int j = 0; j < JB; ++j)
      __builtin_amdgcn_global_load_lds(AS1(Bt + boff[j] + ke),
          AS3(ldsB + (buf * 2 + h) * SZB + j * 8192 + wbase), 16, 0, 0);
  };

  stage(0, 0, 0);
  stage(0, 1, 0);
#pragma unroll
  for (int m = 0; m < FM; ++m)
#pragma unroll
    for (int n = 0; n < FN; ++n)
#pragma unroll
      for (int j = 0; j < 4; ++j) acc[m][n][j] = 0.f;
  asm volatile("s_waitcnt vmcnt(%0)" :: "i"(LPH) : "memory");
  __builtin_amdgcn_s_barrier();

  for (int tp = 0; tp < T / 2 - 1; ++tp) {
    const int t0 = 2 * tp, t1 = 2 * tp + 1;
    PH(t0, 0, 0, true, LPH)
    PH(t0, 1, 0, true, LPH)
    PH(t1, 0, 1, true, LPH)
    PH(t1, 1, 1, true, LPH)
  }
  PH(T - 2, 0, 0, true, LPH)
  PH(T - 2, 1, 0, true, LPH)
  PH(T - 1, 0, 1, false, 0)
  PH(T - 1, 1, 1, false, 0)
}

// ---------- QKV GEMM: [8192 x 3072] = xb[8192x1024] * wcat[3072x1024]^T + bias ----------
// Tile 256x128 (WGM=4, WGN=2, FM=FN=4); grid 24x32 = 768 blocks (3 full rounds).
__global__ __launch_bounds__(512, 2) void qkv_gemm(const u16* __restrict__ xb,
                                                   const u16* __restrict__ wcat,
                                                   const float* __restrict__ bq,
                                                   const float* __restrict__ bk,
                                                   const float* __restrict__ bv,
                                                   u16* __restrict__ qb,
                                                   u16* __restrict__ kb,
                                                   u16* __restrict__ vtb) {
  __shared__ __align__(16) char lds[98304];
  const int tid = threadIdx.x;
  const int bm = blockIdx.y * 256, bn = blockIdx.x * 128;
  f32x4 acc[4][4];
  gemm_engine<4, 4, 4, 2, 16>(xb + bm * 1024, wcat + bn * 1024, 1024, 1024,
                              lds, acc, tid);
  const int l = tid & 63, w = tid >> 6;
  const int wm = w >> 1, wn = w & 1;
  const int which = bn >> 10;  // uniform per block (128 | 1024)
  const float* bias = (which == 0) ? bq : (which == 1) ? bk : bv;
#pragma unroll
  for (int m = 0; m < 4; ++m)
#pragma unroll
    for (int n = 0; n < 4; ++n) {
      int col = bn + wn * 64 + n * 16 + (l & 15);
      int e = col & 1023;
      float bval = bias[e];
#pragma unroll
      for (int j = 0; j < 4; ++j) {
        int row = bm + wm * 64 + m * 16 + (l >> 4) * 4 + j;
        u16 hb = f2b(acc[m][n][j] + bval);
        if (which == 0)      qb[row * 1024 + e] = hb;
        else if (which == 1) kb[row * 1024 + e] = hb;
        else { int b = row >> 11, s = row & 2047; vtb[(b << 21) + e * 2048 + s] = hb; }
      }
    }
}

// ---------- scores GEMM per batch: sb = (q * k^T) / 32, bf16 ----------
// Tile 256x256 (WGM=2, WGN=4, FM=8, FN=4); grid 8x8x4 = 256 blocks.
__global__ __launch_bounds__(512, 2) void scores_gemm(const u16* __restrict__ qb,
                                                      const u16* __restrict__ kb,
                                                      u16* __restrict__ sb) {
  __shared__ __align__(16) char lds[131072];
  const int tid = threadIdx.x;
  const int b = blockIdx.z;
  const int bm = blockIdx.y * 256, bn = blockIdx.x * 256;
  f32x4 acc[8][4];
  gemm_engine<8, 4, 2, 4, 16>(qb + b * (SEQ * DM) + bm * 1024,
                              kb + b * (SEQ * DM) + bn * 1024, 1024, 1024,
                              lds, acc, tid);
  u16* out = sb + (size_t)b * SEQ * SEQ;
  const int l = tid & 63, w = tid >> 6;
  const int wm = w >> 2, wn = w & 3;
#pragma unroll
  for (int m = 0; m < 8; ++m)
#pragma unroll
    for (int n = 0; n < 4; ++n) {
      int col = bn + wn * 64 + n * 16 + (l & 15);
#pragma unroll
      for (int j = 0; j < 4; ++j) {
        int row = bm + wm * 128 + m * 16 + (l >> 4) * 4 + j;
        out[row * 2048 + col] = f2b(acc[m][n][j] * 0.03125f);
      }
    }
}

// ---------- row softmax: 2048-wide rows, bf16 in, bf16 out ----------
__global__ __launch_bounds__(256) void softmax_k(const u16* __restrict__ sb,
                                                 u16* __restrict__ pb) {
  __shared__ float red[8];
  int row = blockIdx.x;
  const u16* src = sb + (size_t)row * 2048;
  u16* dst = pb + (size_t)row * 2048;
  int t = threadIdx.x;
  uint4 raw = *(const uint4*)(src + t * 8);
  uint32_t rw[4] = {raw.x, raw.y, raw.z, raw.w};
  float v[8];
#pragma unroll
  for (int q = 0; q < 4; ++q) {
    v[2 * q]     = b2f(rw[q] & 0xFFFFu);
    v[2 * q + 1] = __builtin_bit_cast(float, rw[q] & 0xFFFF0000u);
  }
  float m = v[0];
#pragma unroll
  for (int j = 1; j < 8; ++j) m = fmaxf(m, v[j]);
  for (int off = 32; off; off >>= 1) m = fmaxf(m, __shfl_xor(m, off));
  int w = t >> 6, l = t & 63;
  if (l == 0) red[w] = m;
  __syncthreads();
  m = fmaxf(fmaxf(red[0], red[1]), fmaxf(red[2], red[3]));
  float e[8], s = 0.f;
#pragma unroll
  for (int j = 0; j < 8; ++j) { e[j] = __expf(v[j] - m); s += e[j]; }
  for (int off = 32; off; off >>= 1) s += __shfl_xor(s, off);
  if (l == 0) red[4 + w] = s;
  __syncthreads();
  s = (red[4] + red[5]) + (red[6] + red[7]);
  float inv = 1.0f / s;
  uint32_t o[4];
#pragma unroll
  for (int q = 0; q < 4; ++q) {
    uint32_t lo = f2b(e[2 * q] * inv);
    uint32_t hi = f2b(e[2 * q + 1] * inv);
    o[q] = lo | (hi << 16);
  }
  *(uint4*)(dst + t * 8) = make_uint4(o[0], o[1], o[2], o[3]);
}

// ---------- PV GEMM per batch: out = pb[2048x2048] * v[2048x1024], fp32 out ----------
// Tile 256x128 (WGM=4, WGN=2, FM=FN=4); grid 8x8x4 = 256 blocks.
__global__ __launch_bounds__(512, 2) void pv_gemm(const u16* __restrict__ pb,
                                                  const u16* __restrict__ vtb,
                                                  float* __restrict__ out) {
  __shared__ __align__(16) char lds[98304];
  const int tid = threadIdx.x;
  const int b = blockIdx.z;
  const int bm = blockIdx.y * 256, bn = blockIdx.x * 128;
  f32x4 acc[4][4];
  gemm_engine<4, 4, 4, 2, 32>(pb + (size_t)b * SEQ * SEQ + bm * 2048,
                              vtb + (size_t)b * DM * SEQ + bn * 2048, 2048, 2048,
                              lds, acc, tid);
  float* o = out + (size_t)b * SEQ * DM;
  const int l = tid & 63, w = tid >> 6;
  const int wm = w >> 1, wn = w & 1;
#pragma unroll
  for (int m = 0; m < 4; ++m)
#pragma unroll
    for (int n = 0; n < 4; ++n) {
      int col = bn + wn * 64 + n * 16 + (l & 15);
#pragma unroll
      for (int j = 0; j < 4; ++j) {
        int row = bm + wm * 64 + m * 16 + (l >> 4) * 4 + j;
        o[row * 1024 + col] = acc[m][n][j];
      }
    }
}

// ---------- launch ----------
extern "C" void kernel_launch(void* const* d_in, const int* in_sizes, int n_in,
                              void* d_out, int out_size, void* d_ws, size_t ws_size,
                              hipStream_t stream) {
  const float* x  = (const float*)d_in[0];
  const float* Wq = (const float*)d_in[1];
  const float* bq = (const float*)d_in[2];
  const float* Wk = (const float*)d_in[3];
  const float* bk = (const float*)d_in[4];
  const float* Wv = (const float*)d_in[5];
  const float* bv = (const float*)d_in[6];
  float* out = (float*)d_out;

  char* ws = (char*)d_ws;
  u16* xb   = (u16*)(ws);                 // 16 MB  bf16 x            [8192][1024]
  u16* wcat = (u16*)(ws + 16777216);      //  6 MB  bf16 Wq|Wk|Wv     [3072][1024]
  u16* qb   = (u16*)(ws + 23068672);      // 16 MB  bf16 q            [4][2048][1024]
  u16* kb   = (u16*)(ws + 39845888);      // 16 MB  bf16 k            [4][2048][1024]
  u16* vtb  = (u16*)(ws + 56623104);      // 16 MB  bf16 v^T          [4][1024][2048]
  u16* sb   = (u16*)(ws + 73400320);      // 32 MB  bf16 scores       [4][2048][2048]
  u16* pb   = (u16*)(ws + 106954752);     // 32 MB  bf16 probs        [4][2048][2048]

  cvt_x_kernel<<<8192, 256, 0, stream>>>(x, xb);
  pack_w_kernel<<<3072, 256, 0, stream>>>(Wq, Wk, Wv, wcat);
  qkv_gemm<<<dim3(24, 32), 512, 0, stream>>>(xb, wcat, bq, bk, bv, qb, kb, vtb);
  scores_gemm<<<dim3(8, 8, 4), 512, 0, stream>>>(qb, kb, sb);
  softmax_k<<<8192, 256, 0, stream>>>(sb, pb);
  pv_gemm<<<dim3(8, 8, 4), 512, 0, stream>>>(pb, vtb, out);
}

// Round 4
// 187.324 us; speedup vs baseline: 1.1502x; 1.0530x over previous
//
#include <hip/hip_runtime.h>
#include <cstdint>

// Fused single-head attention, B=4 S=2048 D=1024, fp32 in/out, bf16 MFMA compute.
// Pipeline: cast/pack -> QKV GEMM (v transposed) -> scores GEMM -> softmax -> PV GEMM.
// GEMM engine: 8 waves (WGM x WGN), per-wave C = FM*16 x FN*16; BK=64 as two
// 32-col half-phases; RING-deep LDS region ring per operand, paired-row XOR
// swizzle (measured 0 bank conflicts); counted vmcnt (steady (RING-3)*LPH,
// never 0 mid-loop); one raw s_barrier per phase; setprio around MFMA cluster.

typedef unsigned short u16;
typedef __attribute__((ext_vector_type(4))) float f32x4;
typedef __attribute__((ext_vector_type(8))) __bf16 bf16x8;

#define AS1(p) ((const __attribute__((address_space(1))) void*)(p))
#define AS3(p) ((__attribute__((address_space(3))) void*)(p))

#define SEQ 2048
#define DM 1024

template <int N> struct ic { static constexpr int v = N; };

// ---------- bf16 bit helpers ----------
__device__ __forceinline__ u16 f2b(float f) {
  uint32_t u = __builtin_bit_cast(uint32_t, f);
  u += 0x7FFFu + ((u >> 16) & 1u);   // RNE
  return (u16)(u >> 16);
}
__device__ __forceinline__ float b2f(uint32_t bits16) {
  return __builtin_bit_cast(float, bits16 << 16);
}

// ---------- converts ----------
__global__ __launch_bounds__(256) void cvt_x_kernel(const float* __restrict__ x,
                                                    u16* __restrict__ xb) {
  int i = (blockIdx.x * 256 + threadIdx.x) * 4;
  float4 v = *(const float4*)(x + i);
  ushort4 o;
  o.x = f2b(v.x); o.y = f2b(v.y); o.z = f2b(v.z); o.w = f2b(v.w);
  *(ushort4*)(xb + i) = o;
}

__global__ __launch_bounds__(256) void pack_w_kernel(const float* __restrict__ Wq,
                                                     const float* __restrict__ Wk,
                                                     const float* __restrict__ Wv,
                                                     u16* __restrict__ wcat) {
  int i = (blockIdx.x * 256 + threadIdx.x) * 4;   // over 3*2^20 elems
  const float* src;
  int j;
  if (i < (1 << 20))      { src = Wq; j = i; }
  else if (i < (2 << 20)) { src = Wk; j = i - (1 << 20); }
  else                    { src = Wv; j = i - (2 << 20); }
  float4 v = *(const float4*)(src + j);
  ushort4 o;
  o.x = f2b(v.x); o.y = f2b(v.y); o.z = f2b(v.z); o.w = f2b(v.w);
  *(ushort4*)(wcat + i) = o;
}

// ---------- pipelined GEMM engine ----------
// Half-region = (rows x 32 cols) bf16, paired-row swizzled:
//   off(row, ch16B) = (row>>1)*128 + (((row&1)*4 + ch) ^ ((row>>1)&7))*16
// (16-lane frag reads hit every bank exactly 2x -> conflict-free; measured 0.)
// Phase hp: [stage half hp+RING-2 -> region (hp+RING-2)%RING] ; ds_read frags
// of region hp%RING ; vmcnt(W) ; s_barrier ; lgkmcnt(0) ; sched_barrier ;
// setprio(1) ; FM*FN MFMA ; setprio(0).
// Cross-wave safety: each wave's vmcnt precedes its barrier, so region hp is
// fully landed (all waves' slices) before any wave's phase-hp reads; a staged
// region's previous readers did lgkmcnt(0) >= 2 barriers earlier.

template <int FM, int FN, int WGM, int WGN, int T, int RING>
__device__ __forceinline__ void gemm_engine(const u16* __restrict__ A,
                                            const u16* __restrict__ Bt,
                                            int lda, int ldb, char* lds,
                                            f32x4 (&acc)[FM][FN], int tid) {
  constexpr int NPH = 2 * T;
  constexpr int RA  = WGM * FM * 16, RB = WGN * FN * 16;
  constexpr int SZA = RA * 64, SZB = RB * 64;
  constexpr int JA  = RA / 128, JB = RB / 128;
  constexpr int LPH = JA + JB;
  constexpr int WS  = (RING - 3) * LPH;   // steady-state vmcnt
  static_assert(NPH > RING, "need at least one steady phase");

  char* ldsA = lds;
  char* ldsB = lds + RING * SZA;

  const int l = tid & 63, w = tid >> 6;
  const int wm = w / WGN, wn = w % WGN;
  const int fr = l & 15, ch = l >> 4;
  const int tb = ((fr >> 1) << 7) + (((((fr & 1) << 2) | ch) ^ (fr >> 1)) << 4);
  const int wmoff = wm * (FM * 1024), wnoff = wn * (FN * 1024);
  const int wbase = (tid & ~63) * 16;     // wave-uniform LDS base

  // inverse-swizzled global source offsets (per thread, per 8KB chunk)
  int aoff[JA], boff[JB];
#pragma unroll
  for (int j = 0; j < JA; ++j) {
    int o  = j * 8192 + tid * 16;
    int rp = o >> 7;
    int cl = ((o >> 4) & 7) ^ (rp & 7);
    aoff[j] = (rp * 2 + (cl >> 2)) * lda + (cl & 3) * 8;
  }
#pragma unroll
  for (int j = 0; j < JB; ++j) {
    int o  = j * 8192 + tid * 16;
    int rp = o >> 7;
    int cl = ((o >> 4) & 7) ^ (rp & 7);
    boff[j] = (rp * 2 + (cl >> 2)) * ldb + (cl & 3) * 8;
  }

  auto stage = [&](int regS, int ke) {
#pragma unroll
    for (int j = 0; j < JA; ++j)
      __builtin_amdgcn_global_load_lds(AS1(A + aoff[j] + ke),
          AS3(ldsA + regS * SZA + j * 8192 + wbase), 16, 0, 0);
#pragma unroll
    for (int j = 0; j < JB; ++j)
      __builtin_amdgcn_global_load_lds(AS1(Bt + boff[j] + ke),
          AS3(ldsB + regS * SZB + j * 8192 + wbase), 16, 0, 0);
  };

  auto phase = [&](auto Wc, auto Sc, int regR, int regS, int keS) {
    constexpr int  WV = decltype(Wc)::v;
    constexpr bool SV = (decltype(Sc)::v != 0);
    if constexpr (SV) stage(regS, keS);
    const char* la = ldsA + regR * SZA + wmoff + tb;
    const char* lb = ldsB + regR * SZB + wnoff + tb;
    bf16x8 af[FM], bfr[FN];
#pragma unroll
    for (int m = 0; m < FM; ++m) af[m] = *(const bf16x8*)(la + m * 1024);
#pragma unroll
    for (int n = 0; n < FN; ++n) bfr[n] = *(const bf16x8*)(lb + n * 1024);
    asm volatile("s_waitcnt vmcnt(%0)" :: "i"(WV) : "memory");
    __builtin_amdgcn_s_barrier();
    asm volatile("s_waitcnt lgkmcnt(0)" ::: "memory");
    __builtin_amdgcn_sched_barrier(0);
    __builtin_amdgcn_s_setprio(1);
#pragma unroll
    for (int m = 0; m < FM; ++m)
#pragma unroll
      for (int n = 0; n < FN; ++n)
        acc[m][n] = __builtin_amdgcn_mfma_f32_16x16x32_bf16(af[m], bfr[n],
                                                            acc[m][n], 0, 0, 0);
    __builtin_amdgcn_s_setprio(0);
  };

  // prologue: stage halves 0..RING-3
#pragma unroll
  for (int p = 0; p < RING - 2; ++p) stage(p, p * 32);
#pragma unroll
  for (int m = 0; m < FM; ++m)
#pragma unroll
    for (int n = 0; n < FN; ++n)
#pragma unroll
      for (int j = 0; j < 4; ++j) acc[m][n][j] = 0.f;
  asm volatile("s_waitcnt vmcnt(%0)" :: "i"(WS) : "memory");
  __builtin_amdgcn_s_barrier();

  int regR = 0, regS = RING - 2, keS = (RING - 2) * 32;
  auto adv = [&](int& r) { r = (r + 1 == RING) ? 0 : r + 1; };

  for (int hp = 0; hp < NPH - RING; ++hp) {
    phase(ic<WS>{}, ic<1>{}, regR, regS, keS);
    adv(regR); adv(regS); keS += 32;
  }
  // tail: RING phases (first RING-2 still stage)
  if constexpr (RING == 4) {
    phase(ic<WS>{}, ic<1>{}, regR, regS, keS); adv(regR); adv(regS); keS += 32;
    phase(ic<WS>{}, ic<1>{}, regR, regS, keS); adv(regR);
    phase(ic<0>{},  ic<0>{}, regR, 0, 0);      adv(regR);
    phase(ic<0>{},  ic<0>{}, regR, 0, 0);
  } else {  // RING == 6
    phase(ic<WS>{},      ic<1>{}, regR, regS, keS); adv(regR); adv(regS); keS += 32;
    phase(ic<WS>{},      ic<1>{}, regR, regS, keS); adv(regR);
    phase(ic<2 * LPH>{}, ic<0>{}, regR, 0, 0);      adv(regR);
    phase(ic<LPH>{},     ic<0>{}, regR, 0, 0);      adv(regR);
    phase(ic<0>{},       ic<0>{}, regR, 0, 0);      adv(regR);
    phase(ic<0>{},       ic<0>{}, regR, 0, 0);
  }
}

// ---------- QKV GEMM: [8192 x 3072] = xb[8192x1024] * wcat[3072x1024]^T + bias ----------
// Tile 256x256 (FM=8,FN=4,WGM=2,WGN=4); 1D grid 384 with XCD-bijective swizzle.
__global__ __launch_bounds__(512, 2) void qkv_gemm(const u16* __restrict__ xb,
                                                   const u16* __restrict__ wcat,
                                                   const float* __restrict__ bq,
                                                   const float* __restrict__ bk,
                                                   const float* __restrict__ bv,
                                                   u16* __restrict__ qb,
                                                   u16* __restrict__ kb,
                                                   u16* __restrict__ vtb) {
  __shared__ __align__(16) char lds[131072];
  const int tid = threadIdx.x;
  const int lin = blockIdx.x;               // 384 = 8 xcd * 48
  const int wgid = (lin & 7) * 48 + (lin >> 3);
  const int bx = wgid % 12, by = wgid / 12;
  const int bm = by * 256, bn = bx * 256;
  f32x4 acc[8][4];
  gemm_engine<8, 4, 2, 4, 16, 4>(xb + bm * 1024, wcat + bn * 1024, 1024, 1024,
                                 lds, acc, tid);
  const int l = tid & 63, w = tid >> 6;
  const int wm = w >> 2, wn = w & 3;
  const int which = bn >> 10;               // uniform per block (256 | 1024)
  const float* bias = (which == 0) ? bq : (which == 1) ? bk : bv;
#pragma unroll
  for (int m = 0; m < 8; ++m)
#pragma unroll
    for (int n = 0; n < 4; ++n) {
      int col = bn + wn * 64 + n * 16 + (l & 15);
      int e = col & 1023;
      float bval = bias[e];
#pragma unroll
      for (int j = 0; j < 4; ++j) {
        int row = bm + wm * 128 + m * 16 + (l >> 4) * 4 + j;
        u16 hb = f2b(acc[m][n][j] + bval);
        if (which == 0)      qb[row * 1024 + e] = hb;
        else if (which == 1) kb[row * 1024 + e] = hb;
        else { int b = row >> 11, s = row & 2047; vtb[(b << 21) + e * 2048 + s] = hb; }
      }
    }
}

// ---------- scores GEMM per batch: sb = (q * k^T) / 32, bf16 ----------
// Tile 256x256; 1D grid 256; XCD swizzle groups same-batch blocks per XCD.
__global__ __launch_bounds__(512, 2) void scores_gemm(const u16* __restrict__ qb,
                                                      const u16* __restrict__ kb,
                                                      u16* __restrict__ sb) {
  __shared__ __align__(16) char lds[131072];
  const int tid = threadIdx.x;
  const int lin = blockIdx.x;               // 256 = 8 xcd * 32
  const int wgid = (lin & 7) * 32 + (lin >> 3);
  const int b = wgid >> 6, r = wgid & 63;
  const int by = r >> 3, bx = r & 7;
  const int bm = by * 256, bn = bx * 256;
  f32x4 acc[8][4];
  gemm_engine<8, 4, 2, 4, 16, 4>(qb + b * (SEQ * DM) + bm * 1024,
                                 kb + b * (SEQ * DM) + bn * 1024, 1024, 1024,
                                 lds, acc, tid);
  u16* out = sb + (size_t)b * SEQ * SEQ;
  const int l = tid & 63, w = tid >> 6;
  const int wm = w >> 2, wn = w & 3;
#pragma unroll
  for (int m = 0; m < 8; ++m)
#pragma unroll
    for (int n = 0; n < 4; ++n) {
      int col = bn + wn * 64 + n * 16 + (l & 15);
#pragma unroll
      for (int j = 0; j < 4; ++j) {
        int row = bm + wm * 128 + m * 16 + (l >> 4) * 4 + j;
        out[row * 2048 + col] = f2b(acc[m][n][j] * 0.03125f);
      }
    }
}

// ---------- row softmax: 2048-wide rows, bf16 in, bf16 out ----------
__global__ __launch_bounds__(256) void softmax_k(const u16* __restrict__ sb,
                                                 u16* __restrict__ pb) {
  __shared__ float red[8];
  int row = blockIdx.x;
  const u16* src = sb + (size_t)row * 2048;
  u16* dst = pb + (size_t)row * 2048;
  int t = threadIdx.x;
  uint4 raw = *(const uint4*)(src + t * 8);
  uint32_t rw[4] = {raw.x, raw.y, raw.z, raw.w};
  float v[8];
#pragma unroll
  for (int q = 0; q < 4; ++q) {
    v[2 * q]     = b2f(rw[q] & 0xFFFFu);
    v[2 * q + 1] = __builtin_bit_cast(float, rw[q] & 0xFFFF0000u);
  }
  float m = v[0];
#pragma unroll
  for (int j = 1; j < 8; ++j) m = fmaxf(m, v[j]);
  for (int off = 32; off; off >>= 1) m = fmaxf(m, __shfl_xor(m, off));
  int w = t >> 6, l = t & 63;
  if (l == 0) red[w] = m;
  __syncthreads();
  m = fmaxf(fmaxf(red[0], red[1]), fmaxf(red[2], red[3]));
  float e[8], s = 0.f;
#pragma unroll
  for (int j = 0; j < 8; ++j) { e[j] = __expf(v[j] - m); s += e[j]; }
  for (int off = 32; off; off >>= 1) s += __shfl_xor(s, off);
  if (l == 0) red[4 + w] = s;
  __syncthreads();
  s = (red[4] + red[5]) + (red[6] + red[7]);
  float inv = 1.0f / s;
  uint32_t o[4];
#pragma unroll
  for (int q = 0; q < 4; ++q) {
    uint32_t lo = f2b(e[2 * q] * inv);
    uint32_t hi = f2b(e[2 * q + 1] * inv);
    o[q] = lo | (hi << 16);
  }
  *(uint4*)(dst + t * 8) = make_uint4(o[0], o[1], o[2], o[3]);
}

// ---------- PV GEMM per batch: out = pb[2048x2048] * v[2048x1024], fp32 out ----------
// Tile 128x256 (FM=4,FN=4); 1D grid 256; RING=6 (depth-3 prefetch for K=2048).
__global__ __launch_bounds__(512, 2) void pv_gemm(const u16* __restrict__ pb,
                                                  const u16* __restrict__ vtb,
                                                  float* __restrict__ out) {
  __shared__ __align__(16) char lds[147456];  // 6*8KB (A) + 6*16KB (B)
  const int tid = threadIdx.x;
  const int lin = blockIdx.x;               // 256 = 8 xcd * 32
  const int wgid = (lin & 7) * 32 + (lin >> 3);
  const int b = wgid >> 6, r = wgid & 63;
  const int by = r >> 2, bx = r & 3;
  const int bm = by * 128, bn = bx * 256;
  f32x4 acc[4][4];
  gemm_engine<4, 4, 2, 4, 32, 6>(pb + (size_t)b * SEQ * SEQ + bm * 2048,
                                 vtb + (size_t)b * DM * SEQ + bn * 2048,
                                 2048, 2048, lds, acc, tid);
  float* o = out + (size_t)b * SEQ * DM;
  const int l = tid & 63, w = tid >> 6;
  const int wm = w >> 2, wn = w & 3;
#pragma unroll
  for (int m = 0; m < 4; ++m)
#pragma unroll
    for (int n = 0; n < 4; ++n) {
      int col = bn + wn * 64 + n * 16 + (l & 15);
#pragma unroll
      for (int j = 0; j < 4; ++j) {
        int row = bm + wm * 64 + m * 16 + (l >> 4) * 4 + j;
        o[row * 1024 + col] = acc[m][n][j];
      }
    }
}

// ---------- launch ----------
extern "C" void kernel_launch(void* const* d_in, const int* in_sizes, int n_in,
                              void* d_out, int out_size, void* d_ws, size_t ws_size,
                              hipStream_t stream) {
  const float* x  = (const float*)d_in[0];
  const float* Wq = (const float*)d_in[1];
  const float* bq = (const float*)d_in[2];
  const float* Wk = (const float*)d_in[3];
  const float* bk = (const float*)d_in[4];
  const float* Wv = (const float*)d_in[5];
  const float* bv = (const float*)d_in[6];
  float* out = (float*)d_out;

  char* ws = (char*)d_ws;
  u16* xb   = (u16*)(ws);                 // 16 MB  bf16 x            [8192][1024]
  u16* wcat = (u16*)(ws + 16777216);      //  6 MB  bf16 Wq|Wk|Wv     [3072][1024]
  u16* qb   = (u16*)(ws + 23068672);      // 16 MB  bf16 q            [4][2048][1024]
  u16* kb   = (u16*)(ws + 39845888);      // 16 MB  bf16 k            [4][2048][1024]
  u16* vtb  = (u16*)(ws + 56623104);      // 16 MB  bf16 v^T          [4][1024][2048]
  u16* sb   = (u16*)(ws + 73400320);      // 32 MB  bf16 scores       [4][2048][2048]
  u16* pb   = (u16*)(ws + 106954752);     // 32 MB  bf16 probs        [4][2048][2048]

  cvt_x_kernel<<<8192, 256, 0, stream>>>(x, xb);
  pack_w_kernel<<<3072, 256, 0, stream>>>(Wq, Wk, Wv, wcat);
  qkv_gemm<<<384, 512, 0, stream>>>(xb, wcat, bq, bk, bv, qb, kb, vtb);
  scores_gemm<<<256, 512, 0, stream>>>(qb, kb, sb);
  softmax_k<<<8192, 256, 0, stream>>>(sb, pb);
  pv_gemm<<<256, 512, 0, stream>>>(pb, vtb, out);
}